// Round 9
// baseline (306.596 us; speedup 1.0000x reference)
//
#include <hip/hip_runtime.h>
#include <cstdint>

// Problem constants (from reference)
#define BB 32
#define TV 8192
#define KK 64
#define TS 128
#define MARGIN_F 0.1f
#define LAMBDA_F 0.5f

typedef unsigned long long u64;
typedef unsigned int u32;

static constexpr int KB_PAIRS = KK * BB;       // 2048 (k,b) rows
static constexpr int W32_PER_B = TV / 32;      // 256 u32 mask words per batch
static constexpr int W64_PER_B = TV / 64;      // 128 u64 mask words per batch

// Workspace layout (u32 units from base):
//   gsa[2048] f32 | gsv[2048] f32 | gca[2048] f32 | len[32] i32 | mw[32] i32
//   vbit[32*256] u32 (32 KB) | pl[32*64*256] u32 (2 MB)
//
// R11: plane v3 = DIRECT GATHER, no LDS, no barriers. History: ballot-chain
// plane = 119us (MLP=1, VGPR 24); R10 LDS-DMA = ~75us (vmcnt(0) drain +
// 2 blocks/CU serial rounds). Insight: a wave gathering gt[b][t][idx[lane]]
// touches 8 x 64B lines per 512B row (50% efficiency, 134MB lines ~= 21us
// floor, less when the ~205MB total footprint is L3-resident), and the 32
// row-loads are independent with VALU-only consumers -> MLP=32 by
// construction; v[32] makes sinking impossible without spills.
// Diagnostics pre-committed: VGPR must be >=40 (<=32 => compiler sank
// loads again -> inline asm next); plane >=50us with VGPR ok => VMEM
// scatter coalescer limit -> pack k-pairs next. reduce/fin byte-identical
// to R9/R10 (measured fast; single-variable discipline).
// R12: identical source — R11 bench was an infra failure (container
// acquisition, same as R4), not a kernel verdict; re-running to measure.

// ---------------------------------------------------------------------------
// K2 v3: direct-gather transpose. Block = 128 rows; wave w owns 32 rows.
// blk = b*64 + tile; wave word g2 = tile*4 + w.
// ---------------------------------------------------------------------------
__global__ __launch_bounds__(256) void plane_kernel(
    const int* __restrict__ idx, const int* __restrict__ gt,
    const int* __restrict__ mv, u32* __restrict__ vbit, u32* __restrict__ pl,
    int* __restrict__ len, int* __restrict__ mw) {
  const int lane = threadIdx.x & 63;
  const int w = threadIdx.x >> 6;              // 0..3
  const int blk = blockIdx.x;
  const int b = blk >> 6;                      // 0..31
  const int tile = blk & 63;                   // 128-row tile
  const int g2 = tile * 4 + w;                 // u32 mask-word index
  const int grow = b * TV + g2 * 32;           // first row of this wave

  // validity ballot for rows [32*g2, 32*g2+32)  (half-ballot, R5-verified)
  const int mvv = (lane < 32) ? mv[grow + lane] : 0;
  const u32 V32 = (u32)__ballot(mvv != 0);
  if (lane == 0) {
    vbit[b * W32_PER_B + g2] = V32;            // always (ws poisoned)
    if (V32) {
      atomicAdd(&len[b], __popc(V32));
      atomicMax(&mw[b], g2);
    }
  }

  u32 plane = 0;
  if (V32) {                                   // wave-uniform (ballot result)
    const int c = idx[lane];                   // lane = k gathers column c
    const int* col = gt + (size_t)grow * TS + c;
    int v[32];                                 // 32 independent loads in flight
#pragma unroll
    for (int r = 0; r < 32; ++r) v[r] = col[r * TS];
#pragma unroll
    for (int r = 0; r < 32; ++r)
      if (v[r] > 0) plane |= 1u << r;
    plane &= V32;                              // aligned requires valid
  }
  // ALWAYS store (ws poisoned; reduce popcounts the whole row)
  pl[(size_t)(b * KK + lane) * W32_PER_B + g2] = plane;
}

// ---------------------------------------------------------------------------
// K3: one block per (k,b) row of pi. Direct stores, no global atomics.
// (byte-identical to R9/R10 — measured fast)
// ---------------------------------------------------------------------------
__global__ __launch_bounds__(256, 4) void reduce_kernel(
    const float* __restrict__ po, const float* __restrict__ pi,
    const u32* __restrict__ vbit, const u32* __restrict__ pl,
    const int* __restrict__ mw,
    float* __restrict__ gsa, float* __restrict__ gsv,
    float* __restrict__ gca) {
  const int tid = threadIdx.x;
  const int lane = tid & 63;
  const int w = tid >> 6;
  const int kb = blockIdx.x;                   // k*BB + b
  const int b = kb & (BB - 1);
  const int k = kb >> 5;
  const u64* plrow = (const u64*)pl + (size_t)(b * KK + k) * W64_PER_B;
  const u64* vrow = (const u64*)vbit + (size_t)b * W64_PER_B;
  const float* pirow = pi + (size_t)kb * TV;
  const float* porow = po + (size_t)b * TV;

  __shared__ float rs[4][2];
  __shared__ int rca;
  if (tid == 0) rca = 0;
  __syncthreads();

  // chunks of 1024 floats; clip by highest valid word (mw in u32-word units)
  const int nch = min(8, (mw[b] + 32) >> 5);
  const int sh = (tid & 15) * 4;               // nibble of this thread's 4 t's
  float sa = 0.f, sv = 0.f;
#pragma unroll 2
  for (int c = 0; c < nch; ++c) {
    const int t = c * 1024 + tid * 4;
    const int widx = t >> 6;                   // u64 word
    const u64 vw = vrow[widx];                 // 16 lanes share -> L1 broadcast
    const u32 vb4 = (u32)((vw >> sh) & 15ull);
    if (vb4) {                                 // aligned subset of valid
      const u64 aw = plrow[widx];
      const u32 ab4 = (u32)((aw >> sh) & 15ull);
      const float4 x = *(const float4*)(pirow + t);
      const float4 p = *(const float4*)(porow + t);   // po: L2-resident (1MB)
      const float e0 =
          fabsf(__fdividef(1.f, 1.f + __expf(-p.x)) -
                __fdividef(1.f, 1.f + __expf(-x.x)));
      const float e1 =
          fabsf(__fdividef(1.f, 1.f + __expf(-p.y)) -
                __fdividef(1.f, 1.f + __expf(-x.y)));
      const float e2 =
          fabsf(__fdividef(1.f, 1.f + __expf(-p.z)) -
                __fdividef(1.f, 1.f + __expf(-x.z)));
      const float e3 =
          fabsf(__fdividef(1.f, 1.f + __expf(-p.w)) -
                __fdividef(1.f, 1.f + __expf(-x.w)));
      if (vb4 & 1u) sv += e0;
      if (vb4 & 2u) sv += e1;
      if (vb4 & 4u) sv += e2;
      if (vb4 & 8u) sv += e3;
      if (ab4 & 1u) sa += e0;
      if (ab4 & 2u) sa += e1;
      if (ab4 & 4u) sa += e2;
      if (ab4 & 8u) sa += e3;
    }
  }
  // 64-lane butterfly, then 4-wave combine
#pragma unroll
  for (int off = 32; off; off >>= 1) {
    sa += __shfl_xor(sa, off);
    sv += __shfl_xor(sv, off);
  }
  if (lane == 0) {
    rs[w][0] = sa;
    rs[w][1] = sv;
  }
  if (tid < W64_PER_B) atomicAdd(&rca, __popcll(plrow[tid]));  // LDS atomic
  __syncthreads();
  if (tid == 0) {
    gsa[kb] = rs[0][0] + rs[1][0] + rs[2][0] + rs[3][0];
    gsv[kb] = rs[0][1] + rs[1][1] + rs[2][1] + rs[3][1];
    gca[kb] = (float)rca;
  }
}

// ---------------------------------------------------------------------------
// Finalize: 1 block over the 2048 (k,b) pairs (logic verified in R2/R3).
// ---------------------------------------------------------------------------
__global__ __launch_bounds__(256) void fin_kernel(
    const float* __restrict__ gsa, const float* __restrict__ gsv,
    const float* __restrict__ gca, const int* __restrict__ len,
    float* __restrict__ out) {
  float s = 0.f;
  for (int i = threadIdx.x; i < KB_PAIRS; i += 256) {
    const int b = i & (BB - 1);
    const float ca = gca[i];
    const float cn = (float)len[b] - ca;
    if (ca > 0.f && cn > 0.f) {
      const float sa = gsa[i];
      const float sv = gsv[i];
      const float d = MARGIN_F - (sa / ca - (sv - sa) / cn);
      s += d > 0.f ? d : 0.f;
    }
  }
#pragma unroll
  for (int off = 32; off > 0; off >>= 1) s += __shfl_down(s, off);
  __shared__ float ws4[4];
  if ((threadIdx.x & 63) == 0) ws4[threadIdx.x >> 6] = s;
  __syncthreads();
  if (threadIdx.x == 0) {
    const float S = ws4[0] + ws4[1] + ws4[2] + ws4[3];
    const float ac = S * (1.0f / (float)KB_PAIRS);
    out[0] = ac;
    out[1] = ac * LAMBDA_F;
  }
}

extern "C" void kernel_launch(void* const* d_in, const int* in_sizes, int n_in,
                              void* d_out, int out_size, void* d_ws, size_t ws_size,
                              hipStream_t stream) {
  const float* pred_orig = (const float*)d_in[0];   // [B,TV] fp32
  const float* pred_int  = (const float*)d_in[1];   // [K,B,TV] fp32
  const int*   idx       = (const int*)d_in[2];     // [K] int32
  const int*   gt        = (const int*)d_in[3];     // [B,TV,TS] int32
  const int*   mv        = (const int*)d_in[4];     // [B,TV] int32
  float* out = (float*)d_out;

  float* gsa = (float*)d_ws;                        // [2048]
  float* gsv = gsa + KB_PAIRS;                      // [2048]
  float* gca = gsv + KB_PAIRS;                      // [2048]
  int*   len = (int*)(gca + KB_PAIRS);              // [32]
  int*   mw  = len + BB;                            // [32]
  u32*   vbit = (u32*)(mw + BB);                    // [32*256]  32 KB
  u32*   pl   = vbit + BB * W32_PER_B;              // [32*64*256] 2 MB

  // only len+mw need zeroing (256 B); everything else is written before read
  hipMemsetAsync(len, 0, 2 * BB * sizeof(int), stream);
  plane_kernel<<<BB * 64, 256, 0, stream>>>(idx, gt, mv, vbit, pl, len, mw);
  reduce_kernel<<<KB_PAIRS, 256, 0, stream>>>(pred_orig, pred_int, vbit, pl,
                                              mw, gsa, gsv, gca);
  fin_kernel<<<1, 256, 0, stream>>>(gsa, gsv, gca, len, out);
}

// Round 10
// 304.814 us; speedup vs baseline: 1.0058x; 1.0058x over previous
//
#include <hip/hip_runtime.h>
#include <cstdint>

// Problem constants (from reference)
#define BB 32
#define TV 8192
#define KK 64
#define TS 128
#define MARGIN_F 0.1f
#define LAMBDA_F 0.5f

typedef unsigned long long u64;
typedef unsigned int u32;

static constexpr int KB_PAIRS = KK * BB;       // 2048 (k,b) rows
static constexpr int W32_PER_B = TV / 32;      // 256 u32 mask words per batch
static constexpr int W64_PER_B = TV / 64;      // 128 u64 mask words per batch

// Workspace layout (u32 units from base):
//   gsa[2048] f32 | gsv[2048] f32 | gca[2048] f32 | len[32] i32 | mw[32] i32
//   vbit[32*256] u32 (32 KB) | pl[32*64*256] u32 (2 MB)
//
// R13: plane v4 = R12's direct gather with ASM-PINNED loads. R12's
// pre-committed diagnostic fired: VGPR=32 => compiler chunked v[32] into
// tiny load/use batches (MLP ~2-4), 95us at VALU 1.5% / occ 60%. Three
// structures (ballot 119, DMA ~75, reg-gather 95) all defeated by hipcc
// re-sinking loads (the guide's m131-m141 pathology). Escape hatch per
// guide: ordered volatile asm. 32 global_load_dword issued back-to-back
// (cannot be re-sunk), one s_waitcnt vmcnt(0), sched_barrier(0) fence
// (rule #18), then consume. Single variable vs R12; reduce/fin identical.
// Prediction: VGPR >= 96 (diagnostic), plane 95 -> 25-45us.
// Pre-committed: plane >= 60us WITH VGPR >= 96 => per-wave MLP is NOT the
// constraint, fabric line-service rate is => pivot to bf16-MFMA GEMM
// formulation ( [E;1] @ (gt>0) per b ) next round.

// ---------------------------------------------------------------------------
// K2 v4: asm-pinned direct-gather transpose. Block = 128 rows; wave w owns
// 32 rows. blk = b*64 + tile; wave word g2 = tile*4 + w.
// ---------------------------------------------------------------------------
__global__ __launch_bounds__(256) void plane_kernel(
    const int* __restrict__ idx, const int* __restrict__ gt,
    const int* __restrict__ mv, u32* __restrict__ vbit, u32* __restrict__ pl,
    int* __restrict__ len, int* __restrict__ mw) {
  const int lane = threadIdx.x & 63;
  const int w = threadIdx.x >> 6;              // 0..3
  const int blk = blockIdx.x;
  const int b = blk >> 6;                      // 0..31
  const int tile = blk & 63;                   // 128-row tile
  const int g2 = tile * 4 + w;                 // u32 mask-word index
  const int grow = b * TV + g2 * 32;           // first row of this wave

  // validity ballot for rows [32*g2, 32*g2+32)  (half-ballot, R5-verified)
  const int mvv = (lane < 32) ? mv[grow + lane] : 0;
  const u32 V32 = (u32)__ballot(mvv != 0);
  if (lane == 0) {
    vbit[b * W32_PER_B + g2] = V32;            // always (ws poisoned)
    if (V32) {
      atomicAdd(&len[b], __popc(V32));
      atomicMax(&mw[b], g2);
    }
  }

  u32 plane = 0;
  if (V32) {                                   // wave-uniform (ballot result)
    const int c = idx[lane];                   // lane = k gathers column c
    const int* col = gt + (size_t)grow * TS + c;
    int v[32];
    // Issue 32 independent loads via ORDERED volatile asm: the compiler
    // cannot sink these to their uses. All 32 stay in flight (MLP=32).
#pragma unroll
    for (int r = 0; r < 32; ++r) {
      asm volatile("global_load_dword %0, %1, off"
                   : "=v"(v[r])
                   : "v"(col + (size_t)r * TS)
                   : "memory");
    }
    asm volatile("s_waitcnt vmcnt(0)" ::: "memory");
    __builtin_amdgcn_sched_barrier(0);         // rule #18: fence consumers
#pragma unroll
    for (int r = 0; r < 32; ++r)
      if (v[r] > 0) plane |= 1u << r;
    plane &= V32;                              // aligned requires valid
  }
  // ALWAYS store (ws poisoned; reduce popcounts the whole row)
  pl[(size_t)(b * KK + lane) * W32_PER_B + g2] = plane;
}

// ---------------------------------------------------------------------------
// K3: one block per (k,b) row of pi. Direct stores, no global atomics.
// (byte-identical to R9/R10/R12 — measured fast)
// ---------------------------------------------------------------------------
__global__ __launch_bounds__(256, 4) void reduce_kernel(
    const float* __restrict__ po, const float* __restrict__ pi,
    const u32* __restrict__ vbit, const u32* __restrict__ pl,
    const int* __restrict__ mw,
    float* __restrict__ gsa, float* __restrict__ gsv,
    float* __restrict__ gca) {
  const int tid = threadIdx.x;
  const int lane = tid & 63;
  const int w = tid >> 6;
  const int kb = blockIdx.x;                   // k*BB + b
  const int b = kb & (BB - 1);
  const int k = kb >> 5;
  const u64* plrow = (const u64*)pl + (size_t)(b * KK + k) * W64_PER_B;
  const u64* vrow = (const u64*)vbit + (size_t)b * W64_PER_B;
  const float* pirow = pi + (size_t)kb * TV;
  const float* porow = po + (size_t)b * TV;

  __shared__ float rs[4][2];
  __shared__ int rca;
  if (tid == 0) rca = 0;
  __syncthreads();

  // chunks of 1024 floats; clip by highest valid word (mw in u32-word units)
  const int nch = min(8, (mw[b] + 32) >> 5);
  const int sh = (tid & 15) * 4;               // nibble of this thread's 4 t's
  float sa = 0.f, sv = 0.f;
#pragma unroll 2
  for (int c = 0; c < nch; ++c) {
    const int t = c * 1024 + tid * 4;
    const int widx = t >> 6;                   // u64 word
    const u64 vw = vrow[widx];                 // 16 lanes share -> L1 broadcast
    const u32 vb4 = (u32)((vw >> sh) & 15ull);
    if (vb4) {                                 // aligned subset of valid
      const u64 aw = plrow[widx];
      const u32 ab4 = (u32)((aw >> sh) & 15ull);
      const float4 x = *(const float4*)(pirow + t);
      const float4 p = *(const float4*)(porow + t);   // po: L2-resident (1MB)
      const float e0 =
          fabsf(__fdividef(1.f, 1.f + __expf(-p.x)) -
                __fdividef(1.f, 1.f + __expf(-x.x)));
      const float e1 =
          fabsf(__fdividef(1.f, 1.f + __expf(-p.y)) -
                __fdividef(1.f, 1.f + __expf(-x.y)));
      const float e2 =
          fabsf(__fdividef(1.f, 1.f + __expf(-p.z)) -
                __fdividef(1.f, 1.f + __expf(-x.z)));
      const float e3 =
          fabsf(__fdividef(1.f, 1.f + __expf(-p.w)) -
                __fdividef(1.f, 1.f + __expf(-x.w)));
      if (vb4 & 1u) sv += e0;
      if (vb4 & 2u) sv += e1;
      if (vb4 & 4u) sv += e2;
      if (vb4 & 8u) sv += e3;
      if (ab4 & 1u) sa += e0;
      if (ab4 & 2u) sa += e1;
      if (ab4 & 4u) sa += e2;
      if (ab4 & 8u) sa += e3;
    }
  }
  // 64-lane butterfly, then 4-wave combine
#pragma unroll
  for (int off = 32; off; off >>= 1) {
    sa += __shfl_xor(sa, off);
    sv += __shfl_xor(sv, off);
  }
  if (lane == 0) {
    rs[w][0] = sa;
    rs[w][1] = sv;
  }
  if (tid < W64_PER_B) atomicAdd(&rca, __popcll(plrow[tid]));  // LDS atomic
  __syncthreads();
  if (tid == 0) {
    gsa[kb] = rs[0][0] + rs[1][0] + rs[2][0] + rs[3][0];
    gsv[kb] = rs[0][1] + rs[1][1] + rs[2][1] + rs[3][1];
    gca[kb] = (float)rca;
  }
}

// ---------------------------------------------------------------------------
// Finalize: 1 block over the 2048 (k,b) pairs (logic verified in R2/R3).
// ---------------------------------------------------------------------------
__global__ __launch_bounds__(256) void fin_kernel(
    const float* __restrict__ gsa, const float* __restrict__ gsv,
    const float* __restrict__ gca, const int* __restrict__ len,
    float* __restrict__ out) {
  float s = 0.f;
  for (int i = threadIdx.x; i < KB_PAIRS; i += 256) {
    const int b = i & (BB - 1);
    const float ca = gca[i];
    const float cn = (float)len[b] - ca;
    if (ca > 0.f && cn > 0.f) {
      const float sa = gsa[i];
      const float sv = gsv[i];
      const float d = MARGIN_F - (sa / ca - (sv - sa) / cn);
      s += d > 0.f ? d : 0.f;
    }
  }
#pragma unroll
  for (int off = 32; off > 0; off >>= 1) s += __shfl_down(s, off);
  __shared__ float ws4[4];
  if ((threadIdx.x & 63) == 0) ws4[threadIdx.x >> 6] = s;
  __syncthreads();
  if (threadIdx.x == 0) {
    const float S = ws4[0] + ws4[1] + ws4[2] + ws4[3];
    const float ac = S * (1.0f / (float)KB_PAIRS);
    out[0] = ac;
    out[1] = ac * LAMBDA_F;
  }
}

extern "C" void kernel_launch(void* const* d_in, const int* in_sizes, int n_in,
                              void* d_out, int out_size, void* d_ws, size_t ws_size,
                              hipStream_t stream) {
  const float* pred_orig = (const float*)d_in[0];   // [B,TV] fp32
  const float* pred_int  = (const float*)d_in[1];   // [K,B,TV] fp32
  const int*   idx       = (const int*)d_in[2];     // [K] int32
  const int*   gt        = (const int*)d_in[3];     // [B,TV,TS] int32
  const int*   mv        = (const int*)d_in[4];     // [B,TV] int32
  float* out = (float*)d_out;

  float* gsa = (float*)d_ws;                        // [2048]
  float* gsv = gsa + KB_PAIRS;                      // [2048]
  float* gca = gsv + KB_PAIRS;                      // [2048]
  int*   len = (int*)(gca + KB_PAIRS);              // [32]
  int*   mw  = len + BB;                            // [32]
  u32*   vbit = (u32*)(mw + BB);                    // [32*256]  32 KB
  u32*   pl   = vbit + BB * W32_PER_B;              // [32*64*256] 2 MB

  // only len+mw need zeroing (256 B); everything else is written before read
  hipMemsetAsync(len, 0, 2 * BB * sizeof(int), stream);
  plane_kernel<<<BB * 64, 256, 0, stream>>>(idx, gt, mv, vbit, pl, len, mw);
  reduce_kernel<<<KB_PAIRS, 256, 0, stream>>>(pred_orig, pred_int, vbit, pl,
                                              mw, gsa, gsv, gca);
  fin_kernel<<<1, 256, 0, stream>>>(gsa, gsv, gca, len, out);
}

// Round 11
// 282.437 us; speedup vs baseline: 1.0855x; 1.0792x over previous
//
#include <hip/hip_runtime.h>
#include <cstdint>

// Problem constants (from reference)
#define BB 32
#define TV 8192
#define KK 64
#define TS 128
#define MARGIN_F 0.1f
#define LAMBDA_F 0.5f

typedef unsigned long long u64;
typedef unsigned int u32;

static constexpr int KB_PAIRS = KK * BB;       // 2048 (k,b) rows
static constexpr int W32_PER_B = TV / 32;      // 256 u32 mask words per batch
static constexpr int W64_PER_B = TV / 64;      // 128 u64 mask words per batch

// Workspace layout (u32 units from base):
//   gsa[2048] f32 | gsv[2048] f32 | gca[2048] f32 | len[32] i32 | mw[32] i32
//   vbit[32*256] u32 (32 KB) | pl[32*128*128] u64 (4 MB)
// pl u64 word for (b, g64, s): pl64[b*16384 + g64*128 + s]; bit r of the
// word = row g64*64 + r (h=r>>5 packed via the two u32 halves).
//
// R14: idx-FREE bitplane packer, single-wave blocks. R13 closed the MLP
// question: asm-pinned 32-deep gather = 95us unchanged (and R10's DMA had
// guaranteed depth at ~75us) -> issue depth is NOT the constraint; the
// scattered-column pattern serves at ~550 GB/s regardless. R10's remaining
// confound: 2 blocks/CU, 64KB drains, multi-wave barriers, scatter-stores.
// R14 ablates that: 64-thr/1-wave blocks, 32-row/16KB tiles (~10 blocks/CU,
// drains 4x smaller), transpose ALL 128 columns (no idx gather; LDS reads
// bank=s%32 = 2-way = free per m136; stores lane-consecutive), skip fully-
// invalid groups (~25%). reduce: plane row = column idx[k], stride-128 u64,
// L2-resident; aligned mask ANDed with valid here (planes carry valid too).
// Prediction: plane 20-35us / VALU 8-15% / FETCH ~50MB; if ~75-95us AGAIN,
// gt->LDS consumption ~1.3TB/s is a platform property -> roofline review.

// ---------------------------------------------------------------------------
// K2 v5: dense DMA + LDS transpose, 1 wave per 32-row group.
// blk = b*256 + g2.
// ---------------------------------------------------------------------------
__global__ __launch_bounds__(64) void plane_kernel(
    const int* __restrict__ gt, const int* __restrict__ mv,
    u32* __restrict__ vbit, u32* __restrict__ pl,
    int* __restrict__ len, int* __restrict__ mw) {
  const int lane = threadIdx.x;                // 0..63
  const int blk = blockIdx.x;
  const int b = blk >> 8;                      // 0..31
  const int g2 = blk & 255;                    // 32-row group
  const int grow = b * TV + g2 * 32;           // first global row

  __shared__ __align__(16) int gtile[32 * TS]; // 16 KB

  // validity ballot for rows [32*g2, 32*g2+32)  (half-ballot, R5-verified)
  const int mvv = (lane < 32) ? mv[grow + lane] : 0;
  const u32 V32 = (u32)__ballot(mvv != 0);
  if (lane == 0) {
    vbit[b * W32_PER_B + g2] = V32;            // always (ws poisoned)
    if (V32) {
      atomicAdd(&len[b], __popc(V32));
      atomicMax(&mw[b], g2);
    }
  }

  // output u32 slots: ((b*128 + g64)*128 + s)*2 + h
  const int g64 = g2 >> 1, h = g2 & 1;
  u32* outp = pl + ((size_t)(b * 128 + g64) * TS) * 2 + h;

  if (V32 == 0u) {                             // wave-uniform: whole wave exits
    outp[2 * lane] = 0u;                       // s = lane
    outp[2 * (lane + 64)] = 0u;                // s = lane + 64
    return;
  }

  // ---- stage 32 rows x 512 B (16 KB) via global->LDS DMA ----
  {
    const char* gsrc = (const char*)(gt + (size_t)grow * TS);
    char* ldst = (char*)gtile;
#pragma unroll
    for (int i = 0; i < 16; ++i) {
      __builtin_amdgcn_global_load_lds(
          (const __attribute__((address_space(1))) u32*)(gsrc + i * 1024 +
                                                         lane * 16),
          (__attribute__((address_space(3))) u32*)(ldst + i * 1024), 16, 0, 0);
    }
  }
  __syncthreads();                             // 1-wave: vmcnt drain + barrier

  // ---- transpose: lane handles columns s = lane and s = lane+64 ----
  // bank = (s + 128*r) % 32 = s % 32 -> 2-way across the wave = conflict-free
#pragma unroll
  for (int p = 0; p < 2; ++p) {
    const int s = lane + 64 * p;
    u32 wbits = 0;
#pragma unroll
    for (int r = 0; r < 32; ++r)
      if (gtile[r * TS + s] > 0) wbits |= 1u << r;
    outp[2 * s] = wbits & V32;                 // aligned requires valid
  }
}

// ---------------------------------------------------------------------------
// K3: one block per (k,b) row of pi. Direct stores, no global atomics.
// Same structure as R9-R13 (measured fast); only plane addressing changed.
// ---------------------------------------------------------------------------
__global__ __launch_bounds__(256, 4) void reduce_kernel(
    const float* __restrict__ po, const float* __restrict__ pi,
    const int* __restrict__ idx,
    const u32* __restrict__ vbit, const u32* __restrict__ pl,
    const int* __restrict__ mw,
    float* __restrict__ gsa, float* __restrict__ gsv,
    float* __restrict__ gca) {
  const int tid = threadIdx.x;
  const int lane = tid & 63;
  const int w = tid >> 6;
  const int kb = blockIdx.x;                   // k*BB + b
  const int b = kb & (BB - 1);
  const int k = kb >> 5;
  const int c = idx[k];                        // this k's sentence column
  // u64 plane word for (b, g64, c): pl64[b*16384 + g64*128 + c]
  const u64* plb = (const u64*)pl + (size_t)b * (128 * TS) + c;
  const u64* vrow = (const u64*)vbit + (size_t)b * W64_PER_B;
  const float* pirow = pi + (size_t)kb * TV;
  const float* porow = po + (size_t)b * TV;

  __shared__ float rs[4][2];
  __shared__ int rca;
  if (tid == 0) rca = 0;
  __syncthreads();

  // chunks of 1024 floats; clip by highest valid word (mw in u32-word units)
  const int nch = min(8, (mw[b] + 32) >> 5);
  const int sh = (tid & 15) * 4;               // nibble of this thread's 4 t's
  float sa = 0.f, sv = 0.f;
#pragma unroll 2
  for (int cc = 0; cc < nch; ++cc) {
    const int t = cc * 1024 + tid * 4;
    const int widx = t >> 6;                   // u64 word (= g64)
    const u64 vw = vrow[widx];                 // 16 lanes share -> L1 broadcast
    const u32 vb4 = (u32)((vw >> sh) & 15ull);
    if (vb4) {                                 // aligned subset of valid
      const u64 aw = plb[(size_t)widx * TS] & vw;
      const u32 ab4 = (u32)((aw >> sh) & 15ull);
      const float4 x = *(const float4*)(pirow + t);
      const float4 p = *(const float4*)(porow + t);   // po: L2-resident (1MB)
      const float e0 =
          fabsf(__fdividef(1.f, 1.f + __expf(-p.x)) -
                __fdividef(1.f, 1.f + __expf(-x.x)));
      const float e1 =
          fabsf(__fdividef(1.f, 1.f + __expf(-p.y)) -
                __fdividef(1.f, 1.f + __expf(-x.y)));
      const float e2 =
          fabsf(__fdividef(1.f, 1.f + __expf(-p.z)) -
                __fdividef(1.f, 1.f + __expf(-x.z)));
      const float e3 =
          fabsf(__fdividef(1.f, 1.f + __expf(-p.w)) -
                __fdividef(1.f, 1.f + __expf(-x.w)));
      if (vb4 & 1u) sv += e0;
      if (vb4 & 2u) sv += e1;
      if (vb4 & 4u) sv += e2;
      if (vb4 & 8u) sv += e3;
      if (ab4 & 1u) sa += e0;
      if (ab4 & 2u) sa += e1;
      if (ab4 & 4u) sa += e2;
      if (ab4 & 8u) sa += e3;
    }
  }
  // 64-lane butterfly, then 4-wave combine
#pragma unroll
  for (int off = 32; off; off >>= 1) {
    sa += __shfl_xor(sa, off);
    sv += __shfl_xor(sv, off);
  }
  if (lane == 0) {
    rs[w][0] = sa;
    rs[w][1] = sv;
  }
  if (tid < W64_PER_B)
    atomicAdd(&rca, __popcll(plb[(size_t)tid * TS] & vrow[tid]));  // LDS atomic
  __syncthreads();
  if (tid == 0) {
    gsa[kb] = rs[0][0] + rs[1][0] + rs[2][0] + rs[3][0];
    gsv[kb] = rs[0][1] + rs[1][1] + rs[2][1] + rs[3][1];
    gca[kb] = (float)rca;
  }
}

// ---------------------------------------------------------------------------
// Finalize: 1 block over the 2048 (k,b) pairs (logic verified in R2/R3).
// ---------------------------------------------------------------------------
__global__ __launch_bounds__(256) void fin_kernel(
    const float* __restrict__ gsa, const float* __restrict__ gsv,
    const float* __restrict__ gca, const int* __restrict__ len,
    float* __restrict__ out) {
  float s = 0.f;
  for (int i = threadIdx.x; i < KB_PAIRS; i += 256) {
    const int b = i & (BB - 1);
    const float ca = gca[i];
    const float cn = (float)len[b] - ca;
    if (ca > 0.f && cn > 0.f) {
      const float sa = gsa[i];
      const float sv = gsv[i];
      const float d = MARGIN_F - (sa / ca - (sv - sa) / cn);
      s += d > 0.f ? d : 0.f;
    }
  }
#pragma unroll
  for (int off = 32; off > 0; off >>= 1) s += __shfl_down(s, off);
  __shared__ float ws4[4];
  if ((threadIdx.x & 63) == 0) ws4[threadIdx.x >> 6] = s;
  __syncthreads();
  if (threadIdx.x == 0) {
    const float S = ws4[0] + ws4[1] + ws4[2] + ws4[3];
    const float ac = S * (1.0f / (float)KB_PAIRS);
    out[0] = ac;
    out[1] = ac * LAMBDA_F;
  }
}

extern "C" void kernel_launch(void* const* d_in, const int* in_sizes, int n_in,
                              void* d_out, int out_size, void* d_ws, size_t ws_size,
                              hipStream_t stream) {
  const float* pred_orig = (const float*)d_in[0];   // [B,TV] fp32
  const float* pred_int  = (const float*)d_in[1];   // [K,B,TV] fp32
  const int*   idx       = (const int*)d_in[2];     // [K] int32
  const int*   gt        = (const int*)d_in[3];     // [B,TV,TS] int32
  const int*   mv        = (const int*)d_in[4];     // [B,TV] int32
  float* out = (float*)d_out;

  float* gsa = (float*)d_ws;                        // [2048]
  float* gsv = gsa + KB_PAIRS;                      // [2048]
  float* gca = gsv + KB_PAIRS;                      // [2048]
  int*   len = (int*)(gca + KB_PAIRS);              // [32]
  int*   mw  = len + BB;                            // [32]
  u32*   vbit = (u32*)(mw + BB);                    // [32*256]  32 KB
  u32*   pl   = vbit + BB * W32_PER_B;              // [32*128*128] u64 = 4 MB

  // only len+mw need zeroing (256 B); everything else is written before read
  hipMemsetAsync(len, 0, 2 * BB * sizeof(int), stream);
  plane_kernel<<<BB * W32_PER_B, 64, 0, stream>>>(gt, mv, vbit, pl, len, mw);
  reduce_kernel<<<KB_PAIRS, 256, 0, stream>>>(pred_orig, pred_int, idx, vbit,
                                              pl, mw, gsa, gsv, gca);
  fin_kernel<<<1, 256, 0, stream>>>(gsa, gsv, gca, len, out);
}